// Round 16
// baseline (248.191 us; speedup 1.0000x reference)
//
#include <hip/hip_runtime.h>
#include <stdint.h>
#include <stddef.h>

#define L_SEQ 2048
#define NB 4
#define NH 16
#define HDIM 64
#define DMODEL 1024
// 1/sqrt(64) * log2(e): softmax computed in exp2 domain
#define ATT_SCALE_L2E 0.1803368801f

typedef __attribute__((ext_vector_type(4))) float f32x4;
typedef __attribute__((ext_vector_type(16))) float f32x16;
typedef __attribute__((ext_vector_type(8))) __bf16 bf16x8;
typedef __attribute__((ext_vector_type(4))) __bf16 bf16x4;

__device__ __forceinline__ void gload16(const void* g, void* l) {
  __builtin_amdgcn_global_load_lds((const __attribute__((address_space(1))) void*)g,
                                   (__attribute__((address_space(3))) void*)l, 16, 0, 0);
}

// ---------------- prep: x fp32 -> bf16 ----------------
__global__ void k_convert_x(const float* __restrict__ x, __bf16* __restrict__ xb) {
  int i = (blockIdx.x * 256 + threadIdx.x) * 4;
  float4 v = *(const float4*)(x + i);
  bf16x4 o;
  o[0] = (__bf16)v.x; o[1] = (__bf16)v.y; o[2] = (__bf16)v.z; o[3] = (__bf16)v.w;
  *(bf16x4*)(xb + i) = o;
}

// ---------------- prep: W (RxC fp32) -> Wt (CxR bf16) ----------------
__global__ void k_transpose_bf16(const float* __restrict__ W, __bf16* __restrict__ Wt,
                                 int R, int C) {
  __shared__ float t[32][33];
  int c0 = blockIdx.x * 32, r0 = blockIdx.y * 32;
  int tx = threadIdx.x, ty = threadIdx.y;  // 32 x 8
#pragma unroll
  for (int i = 0; i < 32; i += 8)
    t[ty + i][tx] = W[(size_t)(r0 + ty + i) * C + c0 + tx];
  __syncthreads();
#pragma unroll
  for (int i = 0; i < 32; i += 8)
    Wt[(size_t)(c0 + ty + i) * R + r0 + tx] = (__bf16)t[tx][ty + i];
}

// ======= barrier-free wave-private GEMM: 64x64 tile per 1-wave block ==========
// Each 64-thread block (one wave) owns a 64x64 output tile with PRIVATE LDS
// (2 x 8KB buffers: A 4KB + B 4KB each). Depth-2 prefetch self-paced by
// per-wave vmcnt(8); ZERO barriers / __syncthreads (the attn kernel's winning
// independence pattern; removes the m114 barrier-drain stall class entirely).
// 16KB LDS/block -> 10 blocks/CU. T2 swizzle kept (lane-index form).
// Safety: buf[t&1] overwrite (STAGE t+2) happens after its ds_reads RETURNED
// (compiler lgkmcnt before MFMA consumption; explicit free lgkmcnt(0) pins it).
// XCD-chunked decode keeps per-XCD working set ~4-5MB (L2-resident).
template <int EPI>
__global__ __launch_bounds__(64) void k_gemmw(
    const __bf16* __restrict__ A, const __bf16* __restrict__ Bt,
    const float* __restrict__ bias, float* __restrict__ Cf,
    __bf16* __restrict__ Qo, __bf16* __restrict__ Ko, __bf16* __restrict__ Vto,
    int K, int N) {
  __shared__ __align__(16) char lds[2 * 8192];

  const int l = threadIdx.x;           // lane (one wave)
  const int g = l >> 4, c16 = l & 15;
  const int fx = ((c16 >> 1) & 3) << 4;

  // XCD-chunked tile decode (bijective; per-XCD: fixed A-slice + B supertiles)
  int im, in;
  const int blk = blockIdx.x;
  const int xcd = blk & 7, local = blk >> 3;
  if (EPI == 0) {                      // QKV: 128 x 48 tiles, 6144 blocks
    int cg = local / 384, r = local - cg * 384;
    im = xcd * 16 + r / 24;
    in = cg * 24 + r % 24;
  } else {                             // out-proj: 128 x 16 tiles, 2048 blocks
    im = xcd * 16 + (local >> 4);
    in = local & 15;
  }
  const int brow = im * 64, bcol = in * 64;

  f32x4 acc[4][4] = {};

  // pre-XOR'd staging source (T2, rule 21): issue i covers LDS rows i*16+(l>>2),
  // slot l&3; f(row)=((row>>1)&3)<<3 elems = ((l>>3)&3)<<3 (i*16 never carries).
  const int scol = ((l & 3) * 8) ^ (((l >> 3) & 3) << 3);
  const __bf16* aSrc = A + (size_t)(brow + (l >> 2)) * K + scol;
  const __bf16* bSrc = Bt + (size_t)(bcol + (l >> 2)) * K + scol;
  const int NT = K >> 5;

#define STAGE(kt, sel) do {                                                   \
    char* lb_ = lds + (sel) * 8192;                                           \
    gload16(aSrc + (kt) * 32, lb_);                                           \
    gload16(aSrc + (size_t)16 * K + (kt) * 32, lb_ + 1024);                   \
    gload16(aSrc + (size_t)32 * K + (kt) * 32, lb_ + 2048);                   \
    gload16(aSrc + (size_t)48 * K + (kt) * 32, lb_ + 3072);                   \
    gload16(bSrc + (kt) * 32, lb_ + 4096);                                    \
    gload16(bSrc + (size_t)16 * K + (kt) * 32, lb_ + 5120);                   \
    gload16(bSrc + (size_t)32 * K + (kt) * 32, lb_ + 6144);                   \
    gload16(bSrc + (size_t)48 * K + (kt) * 32, lb_ + 7168);                   \
  } while (0)

  STAGE(0, 0);
  STAGE(1, 1);

  for (int kt = 0; kt < NT; ++kt) {
    if (kt + 1 < NT)
      asm volatile("s_waitcnt vmcnt(8)" ::: "memory");  // tile kt landed
    else
      asm volatile("s_waitcnt vmcnt(0)" ::: "memory");
    const char* bufA = lds + (kt & 1) * 8192;
    const char* bufB = bufA + 4096;
    bf16x8 af[4], bfr[4];
#pragma unroll
    for (int m = 0; m < 4; ++m)
      af[m] = *(const bf16x8*)(bufA + (m * 16 + c16) * 64 + ((g * 16) ^ fx));
#pragma unroll
    for (int n = 0; n < 4; ++n)
      bfr[n] = *(const bf16x8*)(bufB + (n * 16 + c16) * 64 + ((g * 16) ^ fx));
#pragma unroll
    for (int m = 0; m < 4; ++m)
#pragma unroll
      for (int n = 0; n < 4; ++n)
        acc[m][n] = __builtin_amdgcn_mfma_f32_16x16x32_bf16(af[m], bfr[n], acc[m][n], 0, 0, 0);
    // all ds_reads of buf[kt&1] have returned (consumed by MFMAs); pin it,
    // then it is safe to overwrite with tile kt+2 (wave-private, no barrier).
    asm volatile("s_waitcnt lgkmcnt(0)" ::: "memory");
    if (kt + 2 < NT) STAGE(kt + 2, kt & 1);
  }
#undef STAGE

#pragma unroll
  for (int m = 0; m < 4; ++m) {
#pragma unroll
    for (int n = 0; n < 4; ++n) {
      int gcol = bcol + n * 16 + c16;
      float bv = bias[gcol];
#pragma unroll
      for (int r = 0; r < 4; ++r) {
        int grow = brow + m * 16 + g * 4 + r;
        float v = acc[m][n][r] + bv;
        if (EPI == 0) {
          int which = gcol >> 10, hh = (gcol >> 6) & 15, d = gcol & 63;
          int b = grow >> 11, ll = grow & 2047;
          size_t bh = (size_t)b * NH + hh;
          if (which == 0)
            Qo[(bh * L_SEQ + ll) * HDIM + d] = (__bf16)(v * ATT_SCALE_L2E);
          else if (which == 1)
            Ko[(bh * L_SEQ + ll) * HDIM + d] = (__bf16)v;
          else
            Vto[(bh * HDIM + d) * L_SEQ + ll] = (__bf16)v;
        } else {
          Cf[(size_t)grow * N + gcol] = v;
        }
      }
    }
  }
}

// ---------------- helpers ----------------
__device__ __forceinline__ float fexp2(float x) {
  float r;
  asm("v_exp_f32 %0, %1" : "=v"(r) : "v"(x));
  return r;
}
__device__ __forceinline__ int cvtpk(float a, float b) {
  int r;
  asm("v_cvt_pk_bf16_f32 %0, %1, %2" : "=v"(r) : "v"(a), "v"(b));
  return r;
}
// only safe when a,b are DISTINCT values (distinct registers) — round-4 lesson
__device__ __forceinline__ void pswap(int& a, int& b) {
  asm("v_permlane32_swap_b32 %0, %1" : "+v"(a), "+v"(b));
}
// Build PV A-fragment from 8 in-lane P values (verified rounds 1-3)
__device__ __forceinline__ bf16x8 make_pa(float p0, float p1, float p2, float p3,
                                          float p4, float p5, float p6, float p7) {
  int a0 = cvtpk(p0, p1);
  int a1 = cvtpk(p2, p3);
  int b0 = cvtpk(p4, p5);
  int b1 = cvtpk(p6, p7);
  pswap(a0, b0);
  pswap(a1, b1);
  union { int i[4]; bf16x8 v; } u;
  u.i[0] = a0; u.i[1] = a1; u.i[2] = b0; u.i[3] = b1;
  return u.v;
}

// ---------------- flash attention: constant-shift softmax + la-MFMA row-sum ----
// (round-15 verified)
__global__ __launch_bounds__(256, 4) void k_attn(
    const __bf16* __restrict__ Q, const __bf16* __restrict__ K,
    const __bf16* __restrict__ Vt, __bf16* __restrict__ O) {
  __shared__ char kv_lds[32768];

  const int blk = blockIdx.x;                    // 0..1023
  const int idx = (blk & 7) * 128 + (blk >> 3);  // bijective XCD swizzle
  const int bh = idx >> 4;
  const int qt = idx & 15;
  const int tid = threadIdx.x;
  const int wave = tid >> 6, lane = tid & 63;
  const int r31 = lane & 31, hi = lane >> 5;
  const int swz = (r31 & 7) << 4;
  const int qw = qt * 128 + wave * 32;
  const __bf16* Qb = Q + (size_t)bh * L_SEQ * HDIM;
  const char* Kc = (const char*)(K + (size_t)bh * L_SEQ * HDIM);
  const char* Vc = (const char*)(Vt + (size_t)bh * HDIM * L_SEQ);

  const char* gK0; const char* gK1; const char* gV0; const char* gV1;
  {
    int Y0 = tid * 16, Y1 = 4096 + tid * 16;
    int r0 = Y0 >> 7, r1 = Y1 >> 7;
    int c0 = (Y0 & 127) ^ ((r0 & 7) << 4);
    int c1 = (Y1 & 127) ^ ((r1 & 7) << 4);
    gK0 = Kc + r0 * 128 + c0;
    gK1 = Kc + r1 * 128 + c1;
    gV0 = Vc + (size_t)r0 * 4096 + c0;
    gV1 = Vc + (size_t)r1 * 4096 + c1;
  }

  bf16x8 qf[4];
#pragma unroll
  for (int kc = 0; kc < 4; ++kc)
    qf[kc] = *(const bf16x8*)(Qb + (size_t)(qw + r31) * HDIM + kc * 16 + hi * 8);

  bf16x8 vones;
#pragma unroll
  for (int i = 0; i < 8; ++i) vones[i] = (__bf16)1.0f;

  f32x16 o0 = {}, o1 = {}, la = {};

#define STAGEA(buf, kvb) do {                                                    \
    char* lb_ = kv_lds + (buf) * 16384 + wave * 1024;                            \
    gload16(gK0 + (size_t)(kvb) * 128, lb_);                                     \
    gload16(gK1 + (size_t)(kvb) * 128, lb_ + 4096);                              \
    gload16(gV0 + (kvb) * 2, lb_ + 8192);                                        \
    gload16(gV1 + (kvb) * 2, lb_ + 8192 + 4096);                                 \
  } while (0)

#define BODYL(t, bufo) do {                                                        \
    const char* kb_ = kv_lds + (bufo) + ((t) * 32 + r31) * 128;                    \
    bf16x8 kf0 = *(const bf16x8*)(kb_ + ((hi * 16) ^ swz));                        \
    bf16x8 kf1 = *(const bf16x8*)(kb_ + ((32 + hi * 16) ^ swz));                   \
    bf16x8 kf2 = *(const bf16x8*)(kb_ + ((64 + hi * 16) ^ swz));                   \
    bf16x8 kf3 = *(const bf16x8*)(kb_ + ((96 + hi * 16) ^ swz));                   \
    f32x16 s = {};                                                                 \
    s = __builtin_amdgcn_mfma_f32_32x32x16_bf16(kf0, qf[0], s, 0, 0, 0);           \
    s = __builtin_amdgcn_mfma_f32_32x32x16_bf16(kf1, qf[1], s, 0, 0, 0);           \
    s = __builtin_amdgcn_mfma_f32_32x32x16_bf16(kf2, qf[2], s, 0, 0, 0);           \
    s = __builtin_amdgcn_mfma_f32_32x32x16_bf16(kf3, qf[3], s, 0, 0, 0);           \
    _Pragma("unroll") for (int i = 0; i < 16; ++i) s[i] = fexp2(s[i] - 4.0f);      \
    const char* vb_ = kv_lds + (bufo) + 8192 + r31 * 128;                          \
    bf16x8 pa = make_pa(s[0], s[1], s[2], s[3], s[4], s[5], s[6], s[7]);           \
    o0 = __builtin_amdgcn_mfma_f32_32x32x16_bf16(                                  \
        pa, *(const bf16x8*)(vb_ + (((t) * 64 + hi * 16) ^ swz)), o0, 0, 0, 0);    \
    o1 = __builtin_amdgcn_mfma_f32_32x32x16_bf16(                                  \
        pa, *(const bf16x8*)(vb_ + 4096 + (((t) * 64 + hi * 16) ^ swz)), o1, 0, 0, 0); \
    la = __builtin_amdgcn_mfma_f32_32x32x16_bf16(pa, vones, la, 0, 0, 0);          \
    pa = make_pa(s[8], s[9], s[10], s[11], s[12], s[13], s[14], s[15]);            \
    o0 = __builtin_amdgcn_mfma_f32_32x32x16_bf16(                                  \
        pa, *(const bf16x8*)(vb_ + (((t) * 64 + 32 + hi * 16) ^ swz)), o0, 0, 0, 0); \
    o1 = __builtin_amdgcn_mfma_f32_32x32x16_bf16(                                  \
        pa, *(const bf16x8*)(vb_ + 4096 + (((t) * 64 + 32 + hi * 16) ^ swz)), o1, 0, 0, 0); \
    la = __builtin_amdgcn_mfma_f32_32x32x16_bf16(pa, vones, la, 0, 0, 0);          \
  } while (0)

  int cur = 0;
  STAGEA(0, 0);
  __syncthreads();
  for (int t = 0; t < L_SEQ / 64; ++t) {
    if (t < L_SEQ / 64 - 1) STAGEA(cur ^ 1, (t + 1) * 64);
    BODYL(0, cur * 16384);
    BODYL(1, cur * 16384);
    __syncthreads();
    cur ^= 1;
  }
#undef STAGEA
#undef BODYL

  // la[r] is the softmax denominator for the same row as o0[r]/o1[r]
  const int b = bh >> 4, h = bh & 15;
#pragma unroll
  for (int r = 0; r < 16; ++r) {
    int ql = (r & 3) + 8 * (r >> 2) + 4 * hi;
    float li = 1.f / la[r];
    size_t base = ((size_t)b * L_SEQ + qw + ql) * DMODEL + h * 64 + r31;
    O[base] = (__bf16)(o0[r] * li);
    O[base + 32] = (__bf16)(o1[r] * li);
  }
}

extern "C" void kernel_launch(void* const* d_in, const int* in_sizes, int n_in,
                              void* d_out, int out_size, void* d_ws, size_t ws_size,
                              hipStream_t stream) {
  const float* x = (const float*)d_in[0];
  const float* Wqkv = (const float*)d_in[1];
  const float* bqkv = (const float*)d_in[2];
  const float* Wout = (const float*)d_in[3];
  const float* bout = (const float*)d_in[4];
  float* out = (float*)d_out;

  char* ws = (char*)d_ws;
  __bf16* Xb    = (__bf16*)(ws + 0);
  __bf16* Wqkvt = (__bf16*)(ws + 16777216);
  __bf16* Woutt = (__bf16*)(ws + 23068672);
  __bf16* Qb    = (__bf16*)(ws + 25165824);
  __bf16* Kb    = (__bf16*)(ws + 41943040);
  __bf16* Vtb   = (__bf16*)(ws + 58720256);
  __bf16* Ob    = (__bf16*)(ws + 0);  // reuse Xb region after GEMM1

  k_convert_x<<<8192, 256, 0, stream>>>(x, Xb);
  k_transpose_bf16<<<dim3(96, 32), dim3(32, 8), 0, stream>>>(Wqkv, Wqkvt, 1024, 3072);
  k_transpose_bf16<<<dim3(32, 32), dim3(32, 8), 0, stream>>>(Wout, Woutt, 1024, 1024);
  // QKV projection: M=8192, N=3072 (64x64 tiles, 6144 one-wave blocks)
  k_gemmw<0><<<dim3(6144), 64, 0, stream>>>(Xb, Wqkvt, bqkv, nullptr, Qb, Kb, Vtb,
                                            1024, 3072);
  k_attn<<<dim3(1024), 256, 0, stream>>>(Qb, Kb, Vtb, Ob);
  // output projection: M=8192, N=1024 (64x64 tiles, 2048 one-wave blocks)
  k_gemmw<1><<<dim3(2048), 64, 0, stream>>>(Ob, Woutt, bout, out, nullptr, nullptr,
                                            nullptr, 1024, 1024);
}

// Round 17
// 214.470 us; speedup vs baseline: 1.1572x; 1.1572x over previous
//
#include <hip/hip_runtime.h>
#include <stdint.h>
#include <stddef.h>

#define L_SEQ 2048
#define NB 4
#define NH 16
#define HDIM 64
#define DMODEL 1024
// 1/sqrt(64) * log2(e): softmax computed in exp2 domain
#define ATT_SCALE_L2E 0.1803368801f

typedef __attribute__((ext_vector_type(4))) float f32x4;
typedef __attribute__((ext_vector_type(16))) float f32x16;
typedef __attribute__((ext_vector_type(8))) __bf16 bf16x8;
typedef __attribute__((ext_vector_type(4))) __bf16 bf16x4;

__device__ __forceinline__ void gload16(const void* g, void* l) {
  __builtin_amdgcn_global_load_lds((const __attribute__((address_space(1))) void*)g,
                                   (__attribute__((address_space(3))) void*)l, 16, 0, 0);
}

// ---------------- prep: x fp32 -> bf16 ----------------
__global__ void k_convert_x(const float* __restrict__ x, __bf16* __restrict__ xb) {
  int i = (blockIdx.x * 256 + threadIdx.x) * 4;
  float4 v = *(const float4*)(x + i);
  bf16x4 o;
  o[0] = (__bf16)v.x; o[1] = (__bf16)v.y; o[2] = (__bf16)v.z; o[3] = (__bf16)v.w;
  *(bf16x4*)(xb + i) = o;
}

// ---------------- prep: W (RxC fp32) -> Wt (CxR bf16) ----------------
__global__ void k_transpose_bf16(const float* __restrict__ W, __bf16* __restrict__ Wt,
                                 int R, int C) {
  __shared__ float t[32][33];
  int c0 = blockIdx.x * 32, r0 = blockIdx.y * 32;
  int tx = threadIdx.x, ty = threadIdx.y;  // 32 x 8
#pragma unroll
  for (int i = 0; i < 32; i += 8)
    t[ty + i][tx] = W[(size_t)(r0 + ty + i) * C + c0 + tx];
  __syncthreads();
#pragma unroll
  for (int i = 0; i < 32; i += 8)
    Wt[(size_t)(c0 + ty + i) * R + r0 + tx] = (__bf16)t[tx][ty + i];
}

#define GBAR asm volatile("s_barrier" ::: "memory")

// ======= QKV GEMM: faithful m201 8-phase port. 256x256, BK=64, 8 waves ========
// LDS 128KB = 2 buf x [Ah0|Ah1|Bh0|Bh1] (16KB halves of 128 rows x 128B).
// Per K-tile kt (4 phases, 2 barriers each, setprio around MFMA):
//  P1: ds a0(m0-3) + b0(n0-1) [12 rd]; stage Bh0(kt+1); bar; MFMA a0xb0; bar
//  P2: ds b1(n2-3) [4 rd];            stage Bh1(kt+1); bar; MFMA a0xb1; bar
//  P3: ds a1(m4-7) [8 rd];            stage Ah0(kt+2); bar; MFMA a1xb1; bar
//  P4: (0 rd);     stage Ah1(kt+2); vmcnt(4);          bar; MFMA a1xb0; bar
// Ledger: each stage overwrites a half last-read >=1 phase earlier; vmcnt(4) at
// P4 = next K-tile's halves landed, 4 loads (Ah(kt+2)) in flight across barrier.
__global__ __launch_bounds__(512) void k_gemm8(
    const __bf16* __restrict__ A, const __bf16* __restrict__ Bt,
    const float* __restrict__ bias,
    __bf16* __restrict__ Qo, __bf16* __restrict__ Ko, __bf16* __restrict__ Vto) {
  __shared__ __align__(16) char lds[131072];

  const int tid = threadIdx.x;
  const int wave = tid >> 6, lane = tid & 63;
  const int wr = wave >> 2, wc = wave & 3;
  const int c16 = lane & 15, g = lane >> 4;
  const int fx = (c16 & 7) << 4;          // BK=64 row = 128B -> 8 slots
  // XCD-chunked decode: 384 blocks = 8 x 48; tiles 32(M) x 12(N)
  const int blk = blockIdx.x;
  const int idx = (blk & 7) * 48 + (blk >> 3);
  const int brow = (idx / 12) * 256, bcol = (idx % 12) * 256;

  f32x4 acc[8][4];
#pragma unroll
  for (int m = 0; m < 8; ++m)
#pragma unroll
    for (int n = 0; n < 4; ++n) acc[m][n] = (f32x4){0.f, 0.f, 0.f, 0.f};

  // pre-XOR'd staging sources: 8KB issue = 64 rows x 128B; row = tid>>3,
  // slot = tid&7; source col elems = (slot*8) ^ (((tid>>3)&7)<<3). Row length
  // is exactly one K-tile (64 elems) so the XOR never carries.
  const int scol = ((tid & 7) * 8) ^ (((tid >> 3) & 7) << 3);
  const __bf16* aSrc = A + (size_t)(brow + (tid >> 3)) * 1024 + scol;
  const __bf16* bSrc = Bt + (size_t)(bcol + (tid >> 3)) * 1024 + scol;

#define SAH(h, kt) do {                                                       \
    char* lb_ = lds + (((kt) & 1) << 16) + ((h) << 14) + (wave << 10);        \
    const __bf16* s_ = aSrc + (size_t)(h) * 131072 + (kt) * 64;               \
    gload16(s_, lb_);                                                         \
    gload16(s_ + 65536, lb_ + 8192);                                          \
  } while (0)
#define SBH(h, kt) do {                                                       \
    char* lb_ = lds + (((kt) & 1) << 16) + 32768 + ((h) << 14) + (wave << 10);\
    const __bf16* s_ = bSrc + (size_t)(h) * 131072 + (kt) * 64;               \
    gload16(s_, lb_);                                                         \
    gload16(s_ + 65536, lb_ + 8192);                                          \
  } while (0)

  // prologue: Ah(0), Bh(0), Ah(1) staged; wait Ah(0)+Bh(0) (8 oldest of 12)
  SAH(0, 0); SAH(1, 0); SBH(0, 0); SBH(1, 0); SAH(0, 1); SAH(1, 1);
  asm volatile("s_waitcnt vmcnt(4)" ::: "memory");
  GBAR;

  for (int kt = 0; kt < 16; ++kt) {
    const char* ab = lds + ((kt & 1) << 16) + (wr << 14);
    const char* bb = lds + ((kt & 1) << 16) + 32768 + ((wc >> 1) << 14);
    const int rbase = (wc & 1) * 64;
    bf16x8 a0[4][2], a1[4][2], b0[2][2], b1[2][2];
    // ---- P1: read a0 (m0-3), b0 (n0-1); stage Bh0(kt+1) ----
#pragma unroll
    for (int m = 0; m < 4; ++m)
#pragma unroll
      for (int ks = 0; ks < 2; ++ks)
        a0[m][ks] = *(const bf16x8*)(ab + (m * 16 + c16) * 128 + ((ks * 64 + g * 16) ^ fx));
#pragma unroll
    for (int n = 0; n < 2; ++n)
#pragma unroll
      for (int ks = 0; ks < 2; ++ks)
        b0[n][ks] = *(const bf16x8*)(bb + (rbase + n * 16 + c16) * 128 + ((ks * 64 + g * 16) ^ fx));
    if (kt < 15) SBH(0, kt + 1);
    GBAR;
    __builtin_amdgcn_s_setprio(1);
#pragma unroll
    for (int m = 0; m < 4; ++m)
#pragma unroll
      for (int n = 0; n < 2; ++n)
#pragma unroll
        for (int ks = 0; ks < 2; ++ks)
          acc[m][n] = __builtin_amdgcn_mfma_f32_16x16x32_bf16(a0[m][ks], b0[n][ks], acc[m][n], 0, 0, 0);
    __builtin_amdgcn_s_setprio(0);
    GBAR;
    // ---- P2: read b1 (n2-3); stage Bh1(kt+1) ----
#pragma unroll
    for (int n = 0; n < 2; ++n)
#pragma unroll
      for (int ks = 0; ks < 2; ++ks)
        b1[n][ks] = *(const bf16x8*)(bb + (rbase + (2 + n) * 16 + c16) * 128 + ((ks * 64 + g * 16) ^ fx));
    if (kt < 15) SBH(1, kt + 1);
    GBAR;
    __builtin_amdgcn_s_setprio(1);
#pragma unroll
    for (int m = 0; m < 4; ++m)
#pragma unroll
      for (int n = 0; n < 2; ++n)
#pragma unroll
        for (int ks = 0; ks < 2; ++ks)
          acc[m][2 + n] = __builtin_amdgcn_mfma_f32_16x16x32_bf16(a0[m][ks], b1[n][ks], acc[m][2 + n], 0, 0, 0);
    __builtin_amdgcn_s_setprio(0);
    GBAR;
    // ---- P3: read a1 (m4-7); stage Ah0(kt+2) ----
#pragma unroll
    for (int m = 0; m < 4; ++m)
#pragma unroll
      for (int ks = 0; ks < 2; ++ks)
        a1[m][ks] = *(const bf16x8*)(ab + (64 + m * 16 + c16) * 128 + ((ks * 64 + g * 16) ^ fx));
    if (kt < 14) SAH(0, kt + 2);
    GBAR;
    __builtin_amdgcn_s_setprio(1);
#pragma unroll
    for (int m = 0; m < 4; ++m)
#pragma unroll
      for (int n = 0; n < 2; ++n)
#pragma unroll
        for (int ks = 0; ks < 2; ++ks)
          acc[4 + m][2 + n] = __builtin_amdgcn_mfma_f32_16x16x32_bf16(a1[m][ks], b1[n][ks], acc[4 + m][2 + n], 0, 0, 0);
    __builtin_amdgcn_s_setprio(0);
    GBAR;
    // ---- P4: stage Ah1(kt+2); vmcnt; MFMA a1xb0 ----
    if (kt < 14) {
      SAH(1, kt + 2);
      asm volatile("s_waitcnt vmcnt(4)" ::: "memory");
    } else {
      asm volatile("s_waitcnt vmcnt(0)" ::: "memory");
    }
    GBAR;
    __builtin_amdgcn_s_setprio(1);
#pragma unroll
    for (int m = 0; m < 4; ++m)
#pragma unroll
      for (int n = 0; n < 2; ++n)
#pragma unroll
        for (int ks = 0; ks < 2; ++ks)
          acc[4 + m][n] = __builtin_amdgcn_mfma_f32_16x16x32_bf16(a1[m][ks], b0[n][ks], acc[4 + m][n], 0, 0, 0);
    __builtin_amdgcn_s_setprio(0);
    GBAR;
  }
#undef SAH
#undef SBH

  // epilogue: scatter Q (scaled) / K / V^T
#pragma unroll
  for (int m = 0; m < 8; ++m) {
#pragma unroll
    for (int n = 0; n < 4; ++n) {
      int gcol = bcol + wc * 64 + n * 16 + c16;
      float bv = bias[gcol];
#pragma unroll
      for (int r = 0; r < 4; ++r) {
        int grow = brow + wr * 128 + m * 16 + g * 4 + r;
        float v = acc[m][n][r] + bv;
        int which = gcol >> 10, hh = (gcol >> 6) & 15, d = gcol & 63;
        int b = grow >> 11, ll = grow & 2047;
        size_t bh = (size_t)b * NH + hh;
        if (which == 0)
          Qo[(bh * L_SEQ + ll) * HDIM + d] = (__bf16)(v * ATT_SCALE_L2E);
        else if (which == 1)
          Ko[(bh * L_SEQ + ll) * HDIM + d] = (__bf16)v;
        else
          Vto[(bh * HDIM + d) * L_SEQ + ll] = (__bf16)v;
      }
    }
  }
}

// ------- m97-structure GEMM + T2 swizzle + 3-buffer depth-2 (out-proj) --------
template <int EPI>
__global__ __launch_bounds__(256, 3) void k_gemm(
    const __bf16* __restrict__ A, const __bf16* __restrict__ Bt,
    const float* __restrict__ bias, float* __restrict__ Cf,
    __bf16* __restrict__ Qo, __bf16* __restrict__ Ko, __bf16* __restrict__ Vto,
    int M, int N, int K) {
  __shared__ __align__(16) char lds[3 * 16384];
  const int tid = threadIdx.x;
  const int wave = tid >> 6, lane = tid & 63;
  const int brow = blockIdx.y * 128, bcol = blockIdx.x * 128;
  const int wr = wave >> 1, wc = wave & 1;
  const int g = lane >> 4, c16 = lane & 15;
  const int fx = ((c16 >> 1) & 3) << 4;

  f32x4 acc[4][4] = {};

  const int scol = ((tid & 3) * 8) ^ (((tid >> 3) & 3) << 3);
  const __bf16* aSrc = A + (size_t)(brow + (tid >> 2)) * K + scol;
  const __bf16* bSrc = Bt + (size_t)(bcol + (tid >> 2)) * K + scol;
  const int NT = K >> 5;

#define STAGE(kt, sel) do {                                                   \
    char* lb_ = lds + (sel) * 16384 + wave * 1024;                            \
    gload16(aSrc + (kt) * 32, lb_);                                           \
    gload16(aSrc + (size_t)64 * K + (kt) * 32, lb_ + 4096);                   \
    gload16(bSrc + (kt) * 32, lb_ + 8192);                                    \
    gload16(bSrc + (size_t)64 * K + (kt) * 32, lb_ + 8192 + 4096);            \
  } while (0)

  STAGE(0, 0);
  STAGE(1, 1);
  asm volatile("s_waitcnt vmcnt(4)" ::: "memory");
  GBAR;

  int bs = 0;
  for (int kt = 0; kt < NT; ++kt) {
    if (kt < NT - 2) {
      int sel = (bs == 0) ? 2 : bs - 1;
      STAGE(kt + 2, sel);
    }
    const char* bufA = lds + bs * 16384;
    const char* bufB = bufA + 8192;
    bf16x8 af[4], bfr[4];
#pragma unroll
    for (int m = 0; m < 4; ++m) {
      int rr = wr * 64 + m * 16 + c16;
      af[m] = *(const bf16x8*)(bufA + rr * 64 + ((g * 16) ^ fx));
    }
#pragma unroll
    for (int n = 0; n < 4; ++n) {
      int rr = wc * 64 + n * 16 + c16;
      bfr[n] = *(const bf16x8*)(bufB + rr * 64 + ((g * 16) ^ fx));
    }
#pragma unroll
    for (int m = 0; m < 4; ++m)
#pragma unroll
      for (int n = 0; n < 4; ++n)
        acc[m][n] = __builtin_amdgcn_mfma_f32_16x16x32_bf16(af[m], bfr[n], acc[m][n], 0, 0, 0);
    if (kt < NT - 2)
      asm volatile("s_waitcnt vmcnt(4)" ::: "memory");
    else if (kt == NT - 2)
      asm volatile("s_waitcnt vmcnt(0)" ::: "memory");
    if (kt < NT - 1) GBAR;
    bs = (bs == 2) ? 0 : bs + 1;
  }
#undef STAGE

#pragma unroll
  for (int m = 0; m < 4; ++m) {
#pragma unroll
    for (int n = 0; n < 4; ++n) {
      int gcol = bcol + wc * 64 + n * 16 + c16;
      float bv = bias[gcol];
#pragma unroll
      for (int r = 0; r < 4; ++r) {
        int grow = brow + wr * 64 + m * 16 + g * 4 + r;
        float v = acc[m][n][r] + bv;
        if (EPI == 0) {
          int which = gcol >> 10, hh = (gcol >> 6) & 15, d = gcol & 63;
          int b = grow >> 11, l = grow & 2047;
          size_t bh = (size_t)b * NH + hh;
          if (which == 0)
            Qo[(bh * L_SEQ + l) * HDIM + d] = (__bf16)(v * ATT_SCALE_L2E);
          else if (which == 1)
            Ko[(bh * L_SEQ + l) * HDIM + d] = (__bf16)v;
          else
            Vto[(bh * HDIM + d) * L_SEQ + l] = (__bf16)v;
        } else {
          Cf[(size_t)grow * N + gcol] = v;
        }
      }
    }
  }
}

// ---------------- helpers ----------------
__device__ __forceinline__ float fexp2(float x) {
  float r;
  asm("v_exp_f32 %0, %1" : "=v"(r) : "v"(x));
  return r;
}
__device__ __forceinline__ int cvtpk(float a, float b) {
  int r;
  asm("v_cvt_pk_bf16_f32 %0, %1, %2" : "=v"(r) : "v"(a), "v"(b));
  return r;
}
// only safe when a,b are DISTINCT values (distinct registers) — round-4 lesson
__device__ __forceinline__ void pswap(int& a, int& b) {
  asm("v_permlane32_swap_b32 %0, %1" : "+v"(a), "+v"(b));
}
// Build PV A-fragment from 8 in-lane P values (verified rounds 1-3)
__device__ __forceinline__ bf16x8 make_pa(float p0, float p1, float p2, float p3,
                                          float p4, float p5, float p6, float p7) {
  int a0 = cvtpk(p0, p1);
  int a1 = cvtpk(p2, p3);
  int b0 = cvtpk(p4, p5);
  int b1 = cvtpk(p6, p7);
  pswap(a0, b0);
  pswap(a1, b1);
  union { int i[4]; bf16x8 v; } u;
  u.i[0] = a0; u.i[1] = a1; u.i[2] = b0; u.i[3] = b1;
  return u.v;
}

// ---------------- flash attention (round-15 verified) ----------------
__global__ __launch_bounds__(256, 4) void k_attn(
    const __bf16* __restrict__ Q, const __bf16* __restrict__ K,
    const __bf16* __restrict__ Vt, __bf16* __restrict__ O) {
  __shared__ char kv_lds[32768];

  const int blk = blockIdx.x;                    // 0..1023
  const int idx = (blk & 7) * 128 + (blk >> 3);  // bijective XCD swizzle
  const int bh = idx >> 4;
  const int qt = idx & 15;
  const int tid = threadIdx.x;
  const int wave = tid >> 6, lane = tid & 63;
  const int r31 = lane & 31, hi = lane >> 5;
  const int swz = (r31 & 7) << 4;
  const int qw = qt * 128 + wave * 32;
  const __bf16* Qb = Q + (size_t)bh * L_SEQ * HDIM;
  const char* Kc = (const char*)(K + (size_t)bh * L_SEQ * HDIM);
  const char* Vc = (const char*)(Vt + (size_t)bh * HDIM * L_SEQ);

  const char* gK0; const char* gK1; const char* gV0; const char* gV1;
  {
    int Y0 = tid * 16, Y1 = 4096 + tid * 16;
    int r0 = Y0 >> 7, r1 = Y1 >> 7;
    int c0 = (Y0 & 127) ^ ((r0 & 7) << 4);
    int c1 = (Y1 & 127) ^ ((r1 & 7) << 4);
    gK0 = Kc + r0 * 128 + c0;
    gK1 = Kc + r1 * 128 + c1;
    gV0 = Vc + (size_t)r0 * 4096 + c0;
    gV1 = Vc + (size_t)r1 * 4096 + c1;
  }

  bf16x8 qf[4];
#pragma unroll
  for (int kc = 0; kc < 4; ++kc)
    qf[kc] = *(const bf16x8*)(Qb + (size_t)(qw + r31) * HDIM + kc * 16 + hi * 8);

  bf16x8 vones;
#pragma unroll
  for (int i = 0; i < 8; ++i) vones[i] = (__bf16)1.0f;

  f32x16 o0 = {}, o1 = {}, la = {};

#define STAGEA(buf, kvb) do {                                                    \
    char* lb_ = kv_lds + (buf) * 16384 + wave * 1024;                            \
    gload16(gK0 + (size_t)(kvb) * 128, lb_);                                     \
    gload16(gK1 + (size_t)(kvb) * 128, lb_ + 4096);                              \
    gload16(gV0 + (kvb) * 2, lb_ + 8192);                                        \
    gload16(gV1 + (kvb) * 2, lb_ + 8192 + 4096);                                 \
  } while (0)

#define BODYL(t, bufo) do {                                                        \
    const char* kb_ = kv_lds + (bufo) + ((t) * 32 + r31) * 128;                    \
    bf16x8 kf0 = *(const bf16x8*)(kb_ + ((hi * 16) ^ swz));                        \
    bf16x8 kf1 = *(const bf16x8*)(kb_ + ((32 + hi * 16) ^ swz));                   \
    bf16x8 kf2 = *(const bf16x8*)(kb_ + ((64 + hi * 16) ^ swz));                   \
    bf16x8 kf3 = *(const bf16x8*)(kb_ + ((96 + hi * 16) ^ swz));                   \
    f32x16 s = {};                                                                 \
    s = __builtin_amdgcn_mfma_f32_32x32x16_bf16(kf0, qf[0], s, 0, 0, 0);           \
    s = __builtin_amdgcn_mfma_f32_32x32x16_bf16(kf1, qf[1], s, 0, 0, 0);           \
    s = __builtin_amdgcn_mfma_f32_32x32x16_bf16(kf2, qf[2], s, 0, 0, 0);           \
    s = __builtin_amdgcn_mfma_f32_32x32x16_bf16(kf3, qf[3], s, 0, 0, 0);           \
    _Pragma("unroll") for (int i = 0; i < 16; ++i) s[i] = fexp2(s[i] - 4.0f);      \
    const char* vb_ = kv_lds + (bufo) + 8192 + r31 * 128;                          \
    bf16x8 pa = make_pa(s[0], s[1], s[2], s[3], s[4], s[5], s[6], s[7]);           \
    o0 = __builtin_amdgcn_mfma_f32_32x32x16_bf16(                                  \
        pa, *(const bf16x8*)(vb_ + (((t) * 64 + hi * 16) ^ swz)), o0, 0, 0, 0);    \
    o1 = __builtin_amdgcn_mfma_f32_32x32x16_bf16(                                  \
        pa, *(const bf16x8*)(vb_ + 4096 + (((t) * 64 + hi * 16) ^ swz)), o1, 0, 0, 0); \
    la = __builtin_amdgcn_mfma_f32_32x32x16_bf16(pa, vones, la, 0, 0, 0);          \
    pa = make_pa(s[8], s[9], s[10], s[11], s[12], s[13], s[14], s[15]);            \
    o0 = __builtin_amdgcn_mfma_f32_32x32x16_bf16(                                  \
        pa, *(const bf16x8*)(vb_ + (((t) * 64 + 32 + hi * 16) ^ swz)), o0, 0, 0, 0); \
    o1 = __builtin_amdgcn_mfma_f32_32x32x16_bf16(                                  \
        pa, *(const bf16x8*)(vb_ + 4096 + (((t) * 64 + 32 + hi * 16) ^ swz)), o1, 0, 0, 0); \
    la = __builtin_amdgcn_mfma_f32_32x32x16_bf16(pa, vones, la, 0, 0, 0);          \
  } while (0)

  int cur = 0;
  STAGEA(0, 0);
  __syncthreads();
  for (int t = 0; t < L_SEQ / 64; ++t) {
    if (t < L_SEQ / 64 - 1) STAGEA(cur ^ 1, (t + 1) * 64);
    BODYL(0, cur * 16384);
    BODYL(1, cur * 16384);
    __syncthreads();
    cur ^= 1;
  }
#undef STAGEA
#undef BODYL

  const int b = bh >> 4, h = bh & 15;
#pragma unroll
  for (int r = 0; r < 16; ++r) {
    int ql = (r & 3) + 8 * (r >> 2) + 4 * hi;
    float li = 1.f / la[r];
    size_t base = ((size_t)b * L_SEQ + qw + ql) * DMODEL + h * 64 + r31;
    O[base] = (__bf16)(o0[r] * li);
    O[base + 32] = (__bf16)(o1[r] * li);
  }
}

extern "C" void kernel_launch(void* const* d_in, const int* in_sizes, int n_in,
                              void* d_out, int out_size, void* d_ws, size_t ws_size,
                              hipStream_t stream) {
  const float* x = (const float*)d_in[0];
  const float* Wqkv = (const float*)d_in[1];
  const float* bqkv = (const float*)d_in[2];
  const float* Wout = (const float*)d_in[3];
  const float* bout = (const float*)d_in[4];
  float* out = (float*)d_out;

  char* ws = (char*)d_ws;
  __bf16* Xb    = (__bf16*)(ws + 0);
  __bf16* Wqkvt = (__bf16*)(ws + 16777216);
  __bf16* Woutt = (__bf16*)(ws + 23068672);
  __bf16* Qb    = (__bf16*)(ws + 25165824);
  __bf16* Kb    = (__bf16*)(ws + 41943040);
  __bf16* Vtb   = (__bf16*)(ws + 58720256);
  __bf16* Ob    = (__bf16*)(ws + 0);  // reuse Xb region after GEMM1

  k_convert_x<<<8192, 256, 0, stream>>>(x, Xb);
  k_transpose_bf16<<<dim3(96, 32), dim3(32, 8), 0, stream>>>(Wqkv, Wqkvt, 1024, 3072);
  k_transpose_bf16<<<dim3(32, 32), dim3(32, 8), 0, stream>>>(Wout, Woutt, 1024, 1024);
  // QKV projection: M=8192, N=3072 (256x256 tiles, 384 blocks, 8-phase m201 port)
  k_gemm8<<<dim3(384), 512, 0, stream>>>(Xb, Wqkvt, bqkv, Qb, Kb, Vtb);
  k_attn<<<dim3(1024), 256, 0, stream>>>(Qb, Kb, Vtb, Ob);
  // output projection: M=8192, N=1024 (128x128 tiles, 512 blocks)
  k_gemm<1><<<dim3(8, 64), 256, 0, stream>>>(Ob, Woutt, bout, out, nullptr, nullptr, nullptr,
                                             8192, 1024, 1024);
}